// Round 9
// baseline (2024.546 us; speedup 1.0000x reference)
//
#include <hip/hip_runtime.h>
#include <cstdint>
#include <cstddef>
#include <math.h>

// ---------------------------------------------------------------------------
// RTRBM forward, CD-2 Gibbs, bit-exact JAX threefry (partitionable mode).
// Round 9:
//  - Stage GEMMs back to round-5 geometry (best measured; round-8 swizzle
//    thrashed L2), with 4 i8 slices (scale 2^-32; worst logit err 4.8e-7,
//    RMS ~4e-9 — far below proven Bernoulli margins).
//  - Serial recurrence as ONE persistent kernel with flag-based sync:
//    rotating per-step r buffers + write-through atomic stores + relaxed
//    flag spin. NO grid.sync (round-6: 74 us/step L2 flush). NO per-t
//    weight re-streaming (round-7 lesson).
// ---------------------------------------------------------------------------

#define NVV 4096
#define NHH 1024
#define TT  64
#define BB  32
#define CC  2048
#define NSL 4
#define NCHAIN 64   // blocks in the persistent chain kernel

typedef int v4i  __attribute__((ext_vector_type(4)));
typedef int v16i __attribute__((ext_vector_type(16)));

__constant__ double SC4[NSL] = {0x1p-32, 0x1p-24, 0x1p-16, 0x1p-8};

__host__ __device__ __forceinline__ void tf2x32(uint32_t k0, uint32_t k1,
                                                uint32_t x0, uint32_t x1,
                                                uint32_t& o0, uint32_t& o1) {
  uint32_t ks2 = k0 ^ k1 ^ 0x1BD11BDAu;
#define TF_RND(r) { x0 += x1; x1 = (x1 << (r)) | (x1 >> (32 - (r))); x1 ^= x0; }
  x0 += k0; x1 += k1;
  TF_RND(13) TF_RND(15) TF_RND(26) TF_RND(6)
  x0 += k1;  x1 += ks2 + 1u;
  TF_RND(17) TF_RND(29) TF_RND(16) TF_RND(24)
  x0 += ks2; x1 += k0 + 2u;
  TF_RND(13) TF_RND(15) TF_RND(26) TF_RND(6)
  x0 += k0;  x1 += k1 + 3u;
  TF_RND(17) TF_RND(29) TF_RND(16) TF_RND(24)
  x0 += k1;  x1 += ks2 + 4u;
  TF_RND(13) TF_RND(15) TF_RND(26) TF_RND(6)
  x0 += ks2; x1 += k0 + 5u;
#undef TF_RND
  o0 = x0; o1 = x1;
}

__device__ __forceinline__ float tf_uniform(uint32_t k0, uint32_t k1, uint32_t j) {
  uint32_t o0, o1;
  tf2x32(k0, k1, 0u, j, o0, o1);
  uint32_t bits = o0 ^ o1;
  return __uint_as_float((bits >> 9) | 0x3f800000u) - 1.0f;
}

__device__ __forceinline__ void bern_sample(double logit, uint32_t k0, uint32_t k1,
                                            uint32_t j, float& p32, float& bit) {
  double pd = 1.0 / (1.0 + exp(-logit));
  p32 = (float)pd;
  float u = tf_uniform(k0, k1, j);
  bit = (u < p32) ? 1.0f : 0.0f;
}

__device__ __forceinline__ void step_key(int t, int phase,
                                         uint32_t rk00, uint32_t rk01,
                                         uint32_t rk10, uint32_t rk11,
                                         uint32_t& c0, uint32_t& c1) {
  uint32_t kt0, kt1;
  tf2x32(rk10, rk11, 0u, (uint32_t)(t > 0 ? t - 1 : 0), kt0, kt1);
  if (t == 0) { kt0 = rk00; kt1 = rk01; }
  tf2x32(kt0, kt1, 0u, (uint32_t)phase, c0, c1);
}

// exact 4-byte signed decomposition of round(w * 2^32)
__device__ __forceinline__ void slice4W(float w, signed char sb[NSL]) {
  long long v = __double2ll_rn((double)w * 0x1p32);
#pragma unroll
  for (int s = 0; s < NSL; s++) {
    signed char b = (signed char)(v & 0xFF);
    sb[s] = b;
    v = (v - b) >> 8;
  }
}

// ---------------------------------------------------------------------------
// Prep: W [1024][4096] f32 -> Ws[4][1024][4096] i8 and WsT[4][4096][1024] i8
__global__ __launch_bounds__(256)
void prepW(const float* __restrict__ W, signed char* __restrict__ Ws,
           signed char* __restrict__ WsT) {
  __shared__ float tl[64][65];
  int bi = blockIdx.x >> 6;
  int bj = blockIdx.x & 63;
  int n0 = bi * 64, k0 = bj * 64;
  int tid = threadIdx.x;
#pragma unroll
  for (int it = 0; it < 4; it++) {
    int r = (tid >> 4) + it * 16, c4 = (tid & 15) * 4;
    float4 q = *(const float4*)(W + (size_t)(n0 + r) * NVV + k0 + c4);
    tl[r][c4] = q.x; tl[r][c4 + 1] = q.y; tl[r][c4 + 2] = q.z; tl[r][c4 + 3] = q.w;
  }
  __syncthreads();
#pragma unroll
  for (int it = 0; it < 4; it++) {
    int r = (tid >> 4) + it * 16, c4 = (tid & 15) * 4;
    unsigned int pk[NSL] = {0, 0, 0, 0};
    for (int j = 0; j < 4; j++) {
      signed char sb[NSL]; slice4W(tl[r][c4 + j], sb);
      for (int s = 0; s < NSL; s++) pk[s] |= ((unsigned)(unsigned char)sb[s]) << (8 * j);
    }
    for (int s = 0; s < NSL; s++)
      *(unsigned int*)(Ws + (size_t)s * NHH * NVV + (size_t)(n0 + r) * NVV + k0 + c4) = pk[s];
  }
#pragma unroll
  for (int it = 0; it < 4; it++) {
    int r = (tid >> 4) + it * 16, c4 = (tid & 15) * 4;
    unsigned int pk[NSL] = {0, 0, 0, 0};
    for (int j = 0; j < 4; j++) {
      signed char sb[NSL]; slice4W(tl[c4 + j][r], sb);
      for (int s = 0; s < NSL; s++) pk[s] |= ((unsigned)(unsigned char)sb[s]) << (8 * j);
    }
    for (int s = 0; s < NSL; s++)
      *(unsigned int*)(WsT + (size_t)s * NVV * NHH + (size_t)(k0 + r) * NHH + n0 + c4) = pk[s];
  }
}

// Prep: v [4096][2048] f32 bits -> vT [2048][4096] i8
__global__ __launch_bounds__(256)
void prepVT(const float* __restrict__ v, signed char* __restrict__ vT) {
  __shared__ float tl[64][65];
  int bi = blockIdx.x >> 5;
  int bj = blockIdx.x & 31;
  int i0 = bi * 64, c0 = bj * 64;
  int tid = threadIdx.x;
#pragma unroll
  for (int it = 0; it < 4; it++) {
    int r = (tid >> 4) + it * 16, c4 = (tid & 15) * 4;
    float4 q = *(const float4*)(v + (size_t)(i0 + r) * CC + c0 + c4);
    tl[r][c4] = q.x; tl[r][c4 + 1] = q.y; tl[r][c4 + 2] = q.z; tl[r][c4 + 3] = q.w;
  }
  __syncthreads();
#pragma unroll
  for (int it = 0; it < 4; it++) {
    int cc = (tid >> 4) + it * 16, i4 = (tid & 15) * 4;
    unsigned int pk = 0;
    for (int j = 0; j < 4; j++)
      pk |= ((unsigned)(tl[i4 + j][cc] != 0.0f ? 1 : 0)) << (8 * j);
    *(unsigned int*)(vT + (size_t)(c0 + cc) * NVV + i0 + i4) = pk;
  }
}

// ---------------------------------------------------------------------------
// Stage 0: WvT[c][n] = recombine(vT @ Ws^T). M=2048(c), N=1024(n), K=4096.
// Round-5 geometry: 128c x 64n block, 4 waves, 2 m-tiles/wave share B.
__global__ __launch_bounds__(256)
void s0k(const signed char* __restrict__ vT, const signed char* __restrict__ Ws,
         double* __restrict__ WvT) {
  int wave = threadIdx.x >> 6, lane = threadIdx.x & 63;
  int lrow = lane & 31, lhalf = lane >> 5;
  int xcd = blockIdx.x & 7, idx = blockIdx.x >> 3;
  int bn = xcd * 2 + (idx >> 4);
  int bm = idx & 15;
  int m0 = bm * 128 + (wave & 1) * 64;
  int n0 = bn * 64 + (wave >> 1) * 32;

  v16i acc[2][NSL];
  for (int mt = 0; mt < 2; mt++)
    for (int s = 0; s < NSL; s++)
      for (int e = 0; e < 16; e++) acc[mt][s][e] = 0;

  const signed char* a0 = vT + (size_t)(m0 + lrow) * NVV + 16 * lhalf;
  const signed char* a1 = a0 + (size_t)32 * NVV;
  const signed char* bB = Ws + (size_t)(n0 + lrow) * NVV + 16 * lhalf;
#pragma unroll 2
  for (int kb = 0; kb < NVV; kb += 32) {
    v4i af0 = *(const v4i*)(a0 + kb);
    v4i af1 = *(const v4i*)(a1 + kb);
#pragma unroll
    for (int s = 0; s < NSL; s++) {
      v4i bf = *(const v4i*)(bB + (size_t)s * NHH * NVV + kb);
      acc[0][s] = __builtin_amdgcn_mfma_i32_32x32x32_i8(af0, bf, acc[0][s], 0, 0, 0);
      acc[1][s] = __builtin_amdgcn_mfma_i32_32x32x32_i8(af1, bf, acc[1][s], 0, 0, 0);
    }
  }
#pragma unroll
  for (int mt = 0; mt < 2; mt++)
#pragma unroll
    for (int e = 0; e < 16; e++) {
      int row = (e & 3) + 8 * (e >> 2) + 4 * lhalf;
      double lg = 0;
#pragma unroll
      for (int s = 0; s < NSL; s++) lg += (double)acc[mt][s][e] * SC4[s];
      WvT[(size_t)(m0 + mt * 32 + row) * NHH + n0 + lrow] = lg;
    }
}

// ---------------------------------------------------------------------------
// Persistent chain: all 64 recurrence steps in one launch, flag-synced.
// 64 blocks x 1024 thr; block owns 16 n-rows; U rows cached in LDS.
// r published via device-scope write-through atomic stores into per-step
// buffers (first-touch-per-dispatch => consumers' plain loads are fresh).
__global__ __launch_bounds__(1024)
void chain(const float* __restrict__ U, const double* __restrict__ WvT,
           const float* __restrict__ b_h, const float* __restrict__ b_init,
           float* __restrict__ rt, unsigned char* __restrict__ hT,
           double* __restrict__ hb64, float* __restrict__ rstep,
           unsigned int* __restrict__ flags,
           uint32_t rk00, uint32_t rk01, uint32_t rk10, uint32_t rk11) {
  __shared__ float Ush[16 * NHH];          // 64 KB
  __shared__ double red[16][32][9];        // 36 KB (pad 9 vs 8: bank spread)
  int tid = threadIdx.x;
  int bid = blockIdx.x;

  // entry acquire: drop any stale L2 lines from a previous graph replay
  __builtin_amdgcn_fence(__ATOMIC_ACQUIRE, "agent");

  {
    const float4* src = (const float4*)(U + (size_t)bid * 16 * NHH);
    float4* dst = (float4*)Ush;
    for (int i = tid; i < 4096; i += 1024) dst[i] = src[i];
  }
  __syncthreads();

  int b = tid & 31, ks = (tid >> 5) & 7, rg = tid >> 8;   // b, k-chunk, row-group

  for (int t = 0; t < TT; t++) {
    if (t > 0) {
      if (tid == 0) {
        while (__hip_atomic_load(flags + (size_t)(t - 1) * 16, __ATOMIC_RELAXED,
                                 __HIP_MEMORY_SCOPE_AGENT) < (unsigned)NCHAIN)
          __builtin_amdgcn_s_sleep(4);
      }
      __syncthreads();
      const float* rp = rstep + (size_t)(t - 1) * (BB * NHH) + b * NHH + ks * 128;
      const float* ub = Ush + (rg * 4) * NHH + ks * 128;
      double acc[4] = {0, 0, 0, 0};
#pragma unroll 4
      for (int k = 0; k < 128; k += 4) {
        float4 rq = *(const float4*)(rp + k);
        double r0 = rq.x, r1 = rq.y, r2 = rq.z, r3 = rq.w;
#pragma unroll
        for (int r = 0; r < 4; r++) {
          const float* u = ub + r * NHH + k;
          acc[r] += (double)u[0] * r0 + (double)u[1] * r1 +
                    (double)u[2] * r2 + (double)u[3] * r3;
        }
      }
#pragma unroll
      for (int r = 0; r < 4; r++) red[rg * 4 + r][b][ks] = acc[r];
    }
    __syncthreads();
    if (tid < 512) {
      int rl = tid >> 5, b2 = tid & 31;
      int n = bid * 16 + rl;
      double hbv;
      if (t > 0) {
        double s = 0;
#pragma unroll
        for (int q = 0; q < 8; q++) s += red[rl][b2][q];
        hbv = s + (double)b_h[n];
      } else {
        hbv = (double)b_init[n];
      }
      int c = t * 32 + b2;
      double wv = WvT[(size_t)c * NHH + n];
      uint32_t ck0, ck1;
      step_key(t, 0, rk00, rk01, rk10, rk11, ck0, ck1);
      float p32, bit;
      bern_sample(wv + hbv, ck0, ck1, (uint32_t)(n * 32 + b2), p32, bit);
      rt[(size_t)n * CC + c] = p32;
      hT[(size_t)c * NHH + n] = (unsigned char)(bit != 0.0f ? 1 : 0);
      hb64[(size_t)c * NHH + n] = hbv;
      // publish r through to the coherent point (L3)
      __hip_atomic_store(rstep + (size_t)t * (BB * NHH) + b2 * NHH + n, p32,
                         __ATOMIC_RELAXED, __HIP_MEMORY_SCOPE_AGENT);
    }
    __syncthreads();   // compiler drains vmcnt before s_barrier => stores done
    if (tid == 0 && t + 1 < TT)
      __hip_atomic_fetch_add(flags + (size_t)t * 16, 1u,
                             __ATOMIC_RELEASE, __HIP_MEMORY_SCOPE_AGENT);
  }
}

// ---------------------------------------------------------------------------
// Stages 2/4: out[i][c] = bern(sig(W^T@x + b_v)). Round-5 geometry:
// 64i x 128c block, 4 waves, 2 c-tiles/wave share the 4-slice A operand.
__global__ __launch_bounds__(256, 2)
void sV(const signed char* __restrict__ WsT, const signed char* __restrict__ xT,
        const float* __restrict__ b_v, unsigned char* __restrict__ bitT,
        float* __restrict__ f32out, int phase,
        uint32_t rk00, uint32_t rk01, uint32_t rk10, uint32_t rk11) {
  int wave = threadIdx.x >> 6, lane = threadIdx.x & 63;
  int lrow = lane & 31, lhalf = lane >> 5;
  int xcd = blockIdx.x & 7, idx = blockIdx.x >> 3;
  int bi = xcd * 8 + (idx & 7);
  int bc = idx >> 3;
  int m0 = bi * 64 + (wave & 1) * 32;
  int n0 = bc * 128 + (wave >> 1) * 64;

  v16i acc[2][NSL];
  for (int ct = 0; ct < 2; ct++)
    for (int s = 0; s < NSL; s++)
      for (int e = 0; e < 16; e++) acc[ct][s][e] = 0;

  const signed char* b0 = xT + (size_t)(n0 + lrow) * NHH + 16 * lhalf;
  const signed char* b1 = b0 + (size_t)32 * NHH;
  const signed char* aB = WsT + (size_t)(m0 + lrow) * NHH + 16 * lhalf;
#pragma unroll 2
  for (int kb = 0; kb < NHH; kb += 32) {
    v4i bf0 = *(const v4i*)(b0 + kb);
    v4i bf1 = *(const v4i*)(b1 + kb);
#pragma unroll
    for (int s = 0; s < NSL; s++) {
      v4i af = *(const v4i*)(aB + (size_t)s * NVV * NHH + kb);
      acc[0][s] = __builtin_amdgcn_mfma_i32_32x32x32_i8(af, bf0, acc[0][s], 0, 0, 0);
      acc[1][s] = __builtin_amdgcn_mfma_i32_32x32x32_i8(af, bf1, acc[1][s], 0, 0, 0);
    }
  }

#pragma unroll
  for (int ct = 0; ct < 2; ct++) {
    int tt = (n0 + ct * 32) >> 5;
    uint32_t ck0, ck1;
    step_key(tt, phase, rk00, rk01, rk10, rk11, ck0, ck1);
    int c = n0 + ct * 32 + lrow;
    if (bitT) {
#pragma unroll
      for (int g = 0; g < 4; g++) {
        unsigned int packed = 0;
#pragma unroll
        for (int q = 0; q < 4; q++) {
          int e = g * 4 + q;
          int i = m0 + q + 8 * g + 4 * lhalf;
          double lg = (double)b_v[i];
#pragma unroll
          for (int s = 0; s < NSL; s++) lg += (double)acc[ct][s][e] * SC4[s];
          float p32, bit;
          bern_sample(lg, ck0, ck1, (uint32_t)(i * 32 + lrow), p32, bit);
          (void)p32;
          packed |= ((unsigned)(bit != 0.0f ? 1 : 0)) << (8 * q);
        }
        *(unsigned int*)(bitT + (size_t)c * NVV + m0 + 8 * g + 4 * lhalf) = packed;
      }
    } else {
#pragma unroll
      for (int e = 0; e < 16; e++) {
        int i = m0 + (e & 3) + 8 * (e >> 2) + 4 * lhalf;
        double lg = (double)b_v[i];
#pragma unroll
        for (int s = 0; s < NSL; s++) lg += (double)acc[ct][s][e] * SC4[s];
        float p32, bit;
        bern_sample(lg, ck0, ck1, (uint32_t)(i * 32 + lrow), p32, bit);
        (void)p32;
        f32out[(size_t)i * CC + c] = bit;
      }
    }
  }
}

// Stage 3: logit = W@vm + hb64; sample h2 -> h2T + rmodel. Round-5 geometry.
__global__ __launch_bounds__(256)
void s3k(const signed char* __restrict__ vmT, const signed char* __restrict__ Ws,
         const double* __restrict__ hb64,
         unsigned char* __restrict__ h2T, float* __restrict__ rmodel,
         uint32_t rk00, uint32_t rk01, uint32_t rk10, uint32_t rk11) {
  int wave = threadIdx.x >> 6, lane = threadIdx.x & 63;
  int lrow = lane & 31, lhalf = lane >> 5;
  int xcd = blockIdx.x & 7, idx = blockIdx.x >> 3;
  int bn = xcd * 2 + (idx >> 4);
  int bm = idx & 15;
  int m0 = bm * 128 + (wave & 1) * 64;   // c
  int n0 = bn * 64 + (wave >> 1) * 32;   // n

  v16i acc[2][NSL];
  for (int mt = 0; mt < 2; mt++)
    for (int s = 0; s < NSL; s++)
      for (int e = 0; e < 16; e++) acc[mt][s][e] = 0;

  const signed char* a0 = vmT + (size_t)(m0 + lrow) * NVV + 16 * lhalf;
  const signed char* a1 = a0 + (size_t)32 * NVV;
  const signed char* bB = Ws + (size_t)(n0 + lrow) * NVV + 16 * lhalf;
#pragma unroll 2
  for (int kb = 0; kb < NVV; kb += 32) {
    v4i af0 = *(const v4i*)(a0 + kb);
    v4i af1 = *(const v4i*)(a1 + kb);
#pragma unroll
    for (int s = 0; s < NSL; s++) {
      v4i bf = *(const v4i*)(bB + (size_t)s * NHH * NVV + kb);
      acc[0][s] = __builtin_amdgcn_mfma_i32_32x32x32_i8(af0, bf, acc[0][s], 0, 0, 0);
      acc[1][s] = __builtin_amdgcn_mfma_i32_32x32x32_i8(af1, bf, acc[1][s], 0, 0, 0);
    }
  }

  int n = n0 + lrow;
#pragma unroll
  for (int mt = 0; mt < 2; mt++) {
    int tt = (m0 + mt * 32) >> 5;
    uint32_t ck0, ck1;
    step_key(tt, 2, rk00, rk01, rk10, rk11, ck0, ck1);
#pragma unroll
    for (int e = 0; e < 16; e++) {
      int row = (e & 3) + 8 * (e >> 2) + 4 * lhalf;
      int c = m0 + mt * 32 + row;
      double lg = 0;
#pragma unroll
      for (int s = 0; s < NSL; s++) lg += (double)acc[mt][s][e] * SC4[s];
      lg += hb64[(size_t)c * NHH + n];
      float p32, bit;
      bern_sample(lg, ck0, ck1, (uint32_t)(n * 32 + row), p32, bit);
      (void)p32;
      h2T[(size_t)c * NHH + n] = (unsigned char)(bit != 0.0f ? 1 : 0);
      rmodel[(size_t)n * CC + c] = bit;
    }
  }
}

// ---------------------------------------------------------------------------
static void tf_split(const uint32_t key[2], int n, uint32_t out[][2]) {
  for (int i = 0; i < n; i++)
    tf2x32(key[0], key[1], 0u, (uint32_t)i, out[i][0], out[i][1]);
}

extern "C" void kernel_launch(void* const* d_in, const int* in_sizes, int n_in,
                              void* d_out, int out_size, void* d_ws, size_t ws_size,
                              hipStream_t stream) {
  const float* v      = (const float*)d_in[0];
  const float* W      = (const float*)d_in[1];
  const float* U      = (const float*)d_in[2];
  const float* b_v    = (const float*)d_in[3];
  const float* b_h    = (const float*)d_in[4];
  const float* b_init = (const float*)d_in[5];

  float* out    = (float*)d_out;
  float* vmodel = out;                           // [4096][2048]
  float* rmodel = out + (size_t)NVV * CC;        // [1024][2048]
  float* rt     = rmodel + (size_t)NHH * CC;     // [1024][2048]

  char* wsb = (char*)d_ws;
  signed char* Ws    = (signed char*)wsb;                        // 16 MB
  signed char* WsT   = (signed char*)(wsb + 16777216);           // 16 MB
  signed char* vT    = (signed char*)(wsb + 33554432);           // 8 MB
  signed char* vmT   = (signed char*)(wsb + 41943040);           // 8 MB
  unsigned char* hT  = (unsigned char*)(wsb + 50331648);         // 2 MB
  unsigned char* h2T = (unsigned char*)(wsb + 52428800);         // 2 MB
  double* WvT        = (double*)(wsb + 54525952);                // 16 MB
  double* hb64       = (double*)(wsb + 71303168);                // 16 MB
  float* rstep       = (float*)(wsb + 88080384);                 // 8 MB (64 steps)
  unsigned int* flags= (unsigned int*)(wsb + 96468992);          // 4 KB

  uint32_t root[2] = {0u, 42u};
  uint32_t rk[2][2];  tf_split(root, 2, rk);

  // --- prep ---
  hipLaunchKernelGGL(prepW, dim3(1024), dim3(256), 0, stream, W, Ws, WsT);
  hipLaunchKernelGGL(prepVT, dim3(2048), dim3(256), 0, stream, v, vT);
  hipMemsetAsync(flags, 0, 4096, stream);

  // --- stage 0: WvT = W@v (all t) ---
  hipLaunchKernelGGL(s0k, dim3(256), dim3(256), 0, stream, vT, Ws, WvT);

  // --- stage 1: serial recurrence, one persistent flag-synced launch ---
  hipLaunchKernelGGL(chain, dim3(NCHAIN), dim3(1024), 0, stream,
                     U, WvT, b_h, b_init, rt, hT, hb64, rstep, flags,
                     rk[0][0], rk[0][1], rk[1][0], rk[1][1]);

  // --- stage 2: vm bits -> vmT ---
  hipLaunchKernelGGL(sV, dim3(1024), dim3(256), 0, stream,
                     WsT, (const signed char*)hT, b_v, (unsigned char*)vmT,
                     (float*)nullptr, 1, rk[0][0], rk[0][1], rk[1][0], rk[1][1]);

  // --- stage 3: h2 bits + rmodel ---
  hipLaunchKernelGGL(s3k, dim3(256), dim3(256), 0, stream,
                     vmT, Ws, hb64, h2T, rmodel,
                     rk[0][0], rk[0][1], rk[1][0], rk[1][1]);

  // --- stage 4: vmodel ---
  hipLaunchKernelGGL(sV, dim3(1024), dim3(256), 0, stream,
                     WsT, (const signed char*)h2T, b_v, (unsigned char*)nullptr,
                     vmodel, 3, rk[0][0], rk[0][1], rk[1][0], rk[1][1]);

  (void)in_sizes; (void)n_in; (void)out_size; (void)ws_size;
}